// Round 1
// baseline (31386.160 us; speedup 1.0000x reference)
//
#include <hip/hip_runtime.h>
#include <hip/hip_bf16.h>
#include <math.h>

#define B_ 128
#define T_ 2048
#define D_ 256
#define U_ 512
#define G4_ 2048
#define ALPHA_ 0.001f

#define NGROUP 8     // batch groups
#define GB 16        // samples per group
#define NSLICE 32    // u-slices
#define SU 16        // u per slice
#define NWG 256
#define NTH 256

typedef __attribute__((ext_vector_type(8))) short bf16x8;
typedef __attribute__((ext_vector_type(4))) float f32x4;
typedef __attribute__((ext_vector_type(4))) unsigned short us4;

// workspace layout (bytes)
#define OFF_WBF 0                          // kernel bf16: D_*G4_*2 = 1 MiB
#define OFF_RBF (OFF_WBF + D_*G4_*2)       // recurrent bf16: U_*G4_*2 = 2 MiB
#define OFF_HBUF (OFF_RBF + U_*G4_*2)      // 3 rotating h buffers: 3*B_*U_*2
#define OFF_CNT (OFF_HBUF + 3*B_*U_*2)     // 8 group counters, 256B apart
#define CNT_BYTES (NGROUP*256)

__device__ __forceinline__ unsigned short f2b(float f) {
  unsigned u = __builtin_bit_cast(unsigned, f);
  u += 0x7fffu + ((u >> 16) & 1u);   // round-to-nearest-even bf16
  return (unsigned short)(u >> 16);
}

__global__ void prep_kernel(const float* __restrict__ kern,
                            const float* __restrict__ rker,
                            const float* __restrict__ h0,
                            unsigned short* __restrict__ wbf,
                            unsigned short* __restrict__ rbf,
                            unsigned short* __restrict__ hbuf0) {
  int idx = blockIdx.x * blockDim.x + threadIdx.x;
  int stride = gridDim.x * blockDim.x;
  for (int i = idx; i < D_ * G4_; i += stride) wbf[i] = f2b(kern[i]);
  for (int i = idx; i < U_ * G4_; i += stride) rbf[i] = f2b(rker[i]);
  for (int i = idx; i < B_ * U_; i += stride) hbuf0[i] = f2b(h0[i]);
}

__global__ __launch_bounds__(NTH, 1) void plstm_kernel(
    const float* __restrict__ x, const float* __restrict__ h0,
    const float* __restrict__ c0, const float* __restrict__ t0,
    const float* __restrict__ bias, const float* __restrict__ tg,
    const unsigned short* __restrict__ wbf,
    const unsigned short* __restrict__ rbf,
    unsigned short* hbuf, unsigned* cnt, float* __restrict__ out) {
  const int wg = blockIdx.x;
  const int g = wg >> 5;         // batch group 0..7
  const int sl = wg & 31;        // u-slice 0..31
  const int b0 = g * GB;
  const int u0 = sl * SU;
  const int tid = threadIdx.x;
  const int wave = tid >> 6;     // 0..3  == gate index (i,f,c,o)
  const int lane = tid & 63;

  __shared__ unsigned short h_lds[GB * U_];   // 16 KiB, XOR-swizzled rows
  __shared__ unsigned short x_lds[GB * D_];   // 8 KiB
  __shared__ float z_lds[GB][4 * SU];         // 4 KiB

  // ---- preload B fragments (weights) into registers ----
  bf16x8 br[16], bx[8];
  {
    const int col = wave * U_ + u0 + (lane & 15);
    const int kr0 = (lane >> 4) * 8;
#pragma unroll
    for (int kt = 0; kt < 16; ++kt) {
      bf16x8 v;
#pragma unroll
      for (int jj = 0; jj < 8; ++jj)
        v[jj] = (short)rbf[(kt * 32 + kr0 + jj) * G4_ + col];
      br[kt] = v;
    }
#pragma unroll
    for (int kt = 0; kt < 8; ++kt) {
      bf16x8 v;
#pragma unroll
      for (int jj = 0; jj < 8; ++jj)
        v[jj] = (short)wbf[(kt * 32 + kr0 + jj) * G4_ + col];
      bx[kt] = v;
    }
  }
  const float bias_l = bias[wave * U_ + u0 + (lane & 15)];

  // ---- per-thread recurrent state: thread owns (sample s, u j) ----
  const int s = tid >> 4;
  const int j = tid & 15;
  const int bb = b0 + s;
  const int uu = u0 + j;
  float c_st = c0[bb * U_ + uu];
  float h_st = h0[bb * U_ + uu];
  const float t_0 = t0[bb * U_ + uu];
  const float period = tg[uu];
  const float shift = tg[U_ + uu];
  const float ron = tg[2 * U_ + uu];

  unsigned* mycnt = cnt + g * 64;  // 256 B apart per group

  const int arow = lane & 15;
  const int koff = (lane >> 4) * 16;

  for (int step = 0; step < T_; ++step) {
    const int cur = step % 3;
    const int nxt = (step + 1) % 3;

    // ---- stage h[group] (bf16) into LDS, swizzled ----
    {
      const unsigned short* hsrc = hbuf + cur * (B_ * U_) + b0 * U_;
      const int row = tid >> 4;
#pragma unroll
      for (int it = 0; it < 4; ++it) {
        const int ch = (tid & 15) + it * 16;
        int4 v = *(const int4*)(hsrc + row * U_ + ch * 8);
        int ba = (row * 1024 + ch * 16) ^ ((row & 7) << 4);
        *(int4*)((char*)h_lds + ba) = v;
      }
      // ---- stage x_t (fp32 -> bf16) ----
      const int f0 = (tid & 15) * 16;
      const float* xp = x + ((long)(b0 + row) * T_ + step) * D_ + f0;
#pragma unroll
      for (int q = 0; q < 4; ++q) {
        float4 v = *(const float4*)(xp + q * 4);
        us4 pk = { f2b(v.x), f2b(v.y), f2b(v.z), f2b(v.w) };
        int ba = (row * 512 + (f0 + q * 4) * 2) ^ ((row & 7) << 4);
        *(us4*)((char*)x_lds + ba) = pk;
      }
    }
    __syncthreads();

    // ---- z = h @ Rslice + x_t @ Wslice + bias ----
    f32x4 acc = { bias_l, bias_l, bias_l, bias_l };
#pragma unroll
    for (int kt = 0; kt < 16; ++kt) {
      int ba = (arow * 1024 + kt * 64 + koff) ^ ((arow & 7) << 4);
      bf16x8 a = *(const bf16x8*)((const char*)h_lds + ba);
      acc = __builtin_amdgcn_mfma_f32_16x16x32_bf16(a, br[kt], acc, 0, 0, 0);
    }
#pragma unroll
    for (int kt = 0; kt < 8; ++kt) {
      int ba = (arow * 512 + kt * 64 + koff) ^ ((arow & 7) << 4);
      bf16x8 a = *(const bf16x8*)((const char*)x_lds + ba);
      acc = __builtin_amdgcn_mfma_f32_16x16x32_bf16(a, bx[kt], acc, 0, 0, 0);
    }

    // ---- exchange z tiles (C/D layout: col=lane&15, row=(lane>>4)*4+r) ----
#pragma unroll
    for (int r2 = 0; r2 < 4; ++r2)
      z_lds[(lane >> 4) * 4 + r2][wave * 16 + (lane & 15)] = acc[r2];
    __syncthreads();

    // ---- elementwise gates + phased time gate (fp32) ----
    {
      float zi = z_lds[s][j];
      float zf = z_lds[s][16 + j];
      float zc = z_lds[s][32 + j];
      float zo = z_lds[s][48 + j];
      float ig = fminf(fmaxf(0.2f * zi + 0.5f, 0.f), 1.f);
      float fg = fminf(fmaxf(0.2f * zf + 0.5f, 0.f), 1.f);
      float og = fminf(fmaxf(0.2f * zo + 0.5f, 0.f), 1.f);
      float chat = fg * c_st + ig * tanhf(zc);
      float hhat = og * tanhf(chat);
      float tt = t_0 + (float)(step + 1);
      float xx = tt - shift;
      float ph = (xx - period * floorf(xx / period)) / period;
      float kk = (ph <= 0.5f * ron) ? (2.f * ph / ron)
               : ((ph <= ron) ? (2.f - 2.f * ph / ron) : (ALPHA_ * ph));
      c_st = kk * chat + (1.f - kk) * c_st;
      h_st = kk * hhat + (1.f - kk) * h_st;
      out[((long)bb * T_ + step) * U_ + uu] = h_st;
      hbuf[nxt * (B_ * U_) + bb * U_ + uu] = f2b(h_st);
    }

    // ---- group barrier (32 WGs), release/acquire across XCDs ----
    __syncthreads();   // drains each thread's vmcnt before the fence
    if (tid == 0) {
      __threadfence();                       // release: wb L2
      atomicAdd(mycnt, 1u);
      const unsigned tgt = (unsigned)(step + 1) * NSLICE;
      while (__hip_atomic_load(mycnt, __ATOMIC_RELAXED,
                               __HIP_MEMORY_SCOPE_AGENT) < tgt)
        __builtin_amdgcn_s_sleep(1);
      __threadfence();                       // acquire: inv L1/L2
    }
    __syncthreads();
  }
}

extern "C" void kernel_launch(void* const* d_in, const int* in_sizes, int n_in,
                              void* d_out, int out_size, void* d_ws,
                              size_t ws_size, hipStream_t stream) {
  const float* x    = (const float*)d_in[0];
  const float* h0   = (const float*)d_in[1];
  const float* c0   = (const float*)d_in[2];
  const float* t0   = (const float*)d_in[3];
  const float* kern = (const float*)d_in[4];
  const float* rker = (const float*)d_in[5];
  const float* bias = (const float*)d_in[6];
  const float* tg   = (const float*)d_in[7];
  float* out = (float*)d_out;

  char* ws = (char*)d_ws;
  unsigned short* wbf  = (unsigned short*)(ws + OFF_WBF);
  unsigned short* rbf  = (unsigned short*)(ws + OFF_RBF);
  unsigned short* hbuf = (unsigned short*)(ws + OFF_HBUF);
  unsigned* cnt        = (unsigned*)(ws + OFF_CNT);

  hipMemsetAsync(ws + OFF_CNT, 0, CNT_BYTES, stream);
  prep_kernel<<<1024, 256, 0, stream>>>(kern, rker, h0, wbf, rbf, hbuf);
  plstm_kernel<<<NWG, NTH, 0, stream>>>(x, h0, c0, t0, bias, tg, wbf, rbf,
                                        hbuf, cnt, out);
}

// Round 2
// 5727.889 us; speedup vs baseline: 5.4795x; 5.4795x over previous
//
#include <hip/hip_runtime.h>
#include <hip/hip_bf16.h>
#include <math.h>

#define B_ 128
#define T_ 2048
#define D_ 256
#define U_ 512
#define G4_ 2048
#define ALPHA_ 0.001f

#define NGROUP 8     // batch groups
#define GB 16        // samples per group
#define NSLICE 32    // u-slices
#define SU 16        // u per slice
#define NWG 256
#define NTH 256

typedef __attribute__((ext_vector_type(8))) short bf16x8;
typedef __attribute__((ext_vector_type(4))) float f32x4;
typedef __attribute__((ext_vector_type(4))) unsigned short us4;
typedef __attribute__((ext_vector_type(4))) int i32x4;

// workspace layout (bytes)
#define OFF_WBF 0                          // kernel bf16: D_*G4_*2 = 1 MiB
#define OFF_RBF (OFF_WBF + D_*G4_*2)       // recurrent bf16: U_*G4_*2 = 2 MiB
#define OFF_HBUF (OFF_RBF + U_*G4_*2)      // 3 rotating h buffers: 3*B_*U_*2
#define OFF_CNT (OFF_HBUF + 3*B_*U_*2)     // 8 group counters, 256B apart
#define CNT_BYTES (NGROUP*256)

__device__ __forceinline__ unsigned short f2b(float f) {
  unsigned u = __builtin_bit_cast(unsigned, f);
  u += 0x7fffu + ((u >> 16) & 1u);   // round-to-nearest-even bf16
  return (unsigned short)(u >> 16);
}

__global__ void prep_kernel(const float* __restrict__ kern,
                            const float* __restrict__ rker,
                            const float* __restrict__ h0,
                            unsigned short* __restrict__ wbf,
                            unsigned short* __restrict__ rbf,
                            unsigned short* __restrict__ hbuf0) {
  int idx = blockIdx.x * blockDim.x + threadIdx.x;
  int stride = gridDim.x * blockDim.x;
  for (int i = idx; i < D_ * G4_; i += stride) wbf[i] = f2b(kern[i]);
  for (int i = idx; i < U_ * G4_; i += stride) rbf[i] = f2b(rker[i]);
  for (int i = idx; i < B_ * U_; i += stride) hbuf0[i] = f2b(h0[i]);
}

__global__ __launch_bounds__(NTH, 1) void plstm_kernel(
    const float* __restrict__ x, const float* __restrict__ h0,
    const float* __restrict__ c0, const float* __restrict__ t0,
    const float* __restrict__ bias, const float* __restrict__ tg,
    const unsigned short* __restrict__ wbf,
    const unsigned short* __restrict__ rbf,
    unsigned short* hbuf, unsigned* cnt, float* __restrict__ out) {
  const int wg = blockIdx.x;
  const int g = wg >> 5;         // batch group 0..7
  const int sl = wg & 31;        // u-slice 0..31
  const int b0 = g * GB;
  const int u0 = sl * SU;
  const int tid = threadIdx.x;
  const int wave = tid >> 6;     // 0..3  == gate index (i,f,c,o)
  const int lane = tid & 63;

  __shared__ unsigned short h_lds[GB * U_];      // 16 KiB, XOR-swizzled rows
  __shared__ unsigned short x_lds[2][GB * D_];   // 2 x 8 KiB (double buffer)
  __shared__ float z_lds[GB][4 * SU];            // 4 KiB

  // ---- preload B fragments (weights) into registers (cached loads, once) ----
  bf16x8 br[16], bx[8];
  {
    const int col = wave * U_ + u0 + (lane & 15);
    const int kr0 = (lane >> 4) * 8;
#pragma unroll
    for (int kt = 0; kt < 16; ++kt) {
      bf16x8 v;
#pragma unroll
      for (int jj = 0; jj < 8; ++jj)
        v[jj] = (short)rbf[(kt * 32 + kr0 + jj) * G4_ + col];
      br[kt] = v;
    }
#pragma unroll
    for (int kt = 0; kt < 8; ++kt) {
      bf16x8 v;
#pragma unroll
      for (int jj = 0; jj < 8; ++jj)
        v[jj] = (short)wbf[(kt * 32 + kr0 + jj) * G4_ + col];
      bx[kt] = v;
    }
  }
  const float bias_l = bias[wave * U_ + u0 + (lane & 15)];

  // ---- per-thread recurrent state: thread owns (sample s, u j) ----
  const int s = tid >> 4;
  const int j = tid & 15;
  const int bb = b0 + s;
  const int uu = u0 + j;
  float c_st = c0[bb * U_ + uu];
  float h_st = h0[bb * U_ + uu];
  const float t_0 = t0[bb * U_ + uu];
  const float period = tg[uu];
  const float shift = tg[U_ + uu];
  const float ron = tg[2 * U_ + uu];

  unsigned* mycnt = cnt + g * 64;  // 256 B apart per group

  const int arow = lane & 15;
  const int koff = (lane >> 4) * 16;

  // ---- x staging: fp32 -> bf16 -> swizzled LDS (cached loads, read-only) ----
  auto stage_x = [&](int t, int buf) {
    const int row = tid >> 4;
    const int f0 = (tid & 15) * 16;
    const float* xp = x + ((long)(b0 + row) * T_ + t) * D_ + f0;
    char* base = (char*)&x_lds[buf][0];
#pragma unroll
    for (int q = 0; q < 4; ++q) {
      float4 v = *(const float4*)(xp + q * 4);
      us4 pk = { f2b(v.x), f2b(v.y), f2b(v.z), f2b(v.w) };
      int ba = (row * 512 + (f0 + q * 4) * 2) ^ ((row & 7) << 4);
      *(us4*)(base + ba) = pk;
    }
  };

  stage_x(0, 0);   // prologue; sync below covers it

  for (int step = 0; step < T_; ++step) {
    const int cur = step % 3;
    const int nxt = (step + 1) % 3;
    const int xb = step & 1;

    // ---- (1) coherent (L2-bypass) load of group h slice -> swizzled LDS ----
    {
      const unsigned short* hsrc = hbuf + cur * (B_ * U_) + b0 * U_;
      const int row = tid >> 4;
      const int ch = tid & 15;
      const unsigned short* p0 = hsrc + row * U_ + (ch + 0) * 8;
      const unsigned short* p1 = hsrc + row * U_ + (ch + 16) * 8;
      const unsigned short* p2 = hsrc + row * U_ + (ch + 32) * 8;
      const unsigned short* p3 = hsrc + row * U_ + (ch + 48) * 8;
      i32x4 v0, v1, v2, v3;
      asm volatile(
          "global_load_dwordx4 %0, %4, off sc0 sc1\n\t"
          "global_load_dwordx4 %1, %5, off sc0 sc1\n\t"
          "global_load_dwordx4 %2, %6, off sc0 sc1\n\t"
          "global_load_dwordx4 %3, %7, off sc0 sc1\n\t"
          "s_waitcnt vmcnt(0)"
          : "=&v"(v0), "=&v"(v1), "=&v"(v2), "=&v"(v3)
          : "v"(p0), "v"(p1), "v"(p2), "v"(p3)
          : "memory");
      __builtin_amdgcn_sched_barrier(0);
      char* hb = (char*)h_lds;
      *(i32x4*)(hb + ((row * 1024 + (ch + 0) * 16) ^ ((row & 7) << 4))) = v0;
      *(i32x4*)(hb + ((row * 1024 + (ch + 16) * 16) ^ ((row & 7) << 4))) = v1;
      *(i32x4*)(hb + ((row * 1024 + (ch + 32) * 16) ^ ((row & 7) << 4))) = v2;
      *(i32x4*)(hb + ((row * 1024 + (ch + 48) * 16) ^ ((row & 7) << 4))) = v3;
    }
    __syncthreads();

    // ---- (2) z = h @ Rslice + x_t @ Wslice + bias ----
    f32x4 acc = { bias_l, bias_l, bias_l, bias_l };
#pragma unroll
    for (int kt = 0; kt < 16; ++kt) {
      int ba = (arow * 1024 + kt * 64 + koff) ^ ((arow & 7) << 4);
      bf16x8 a = *(const bf16x8*)((const char*)h_lds + ba);
      acc = __builtin_amdgcn_mfma_f32_16x16x32_bf16(a, br[kt], acc, 0, 0, 0);
    }
    {
      const char* xbase = (const char*)&x_lds[xb][0];
#pragma unroll
      for (int kt = 0; kt < 8; ++kt) {
        int ba = (arow * 512 + kt * 64 + koff) ^ ((arow & 7) << 4);
        bf16x8 a = *(const bf16x8*)(xbase + ba);
        acc = __builtin_amdgcn_mfma_f32_16x16x32_bf16(a, bx[kt], acc, 0, 0, 0);
      }
    }

    // ---- (3) exchange z tiles (C/D: col=lane&15, row=(lane>>4)*4+r) ----
#pragma unroll
    for (int r2 = 0; r2 < 4; ++r2)
      z_lds[(lane >> 4) * 4 + r2][wave * 16 + (lane & 15)] = acc[r2];
    __syncthreads();

    // ---- (4) elementwise gates + phased time gate (fp32) ----
    {
      float zi = z_lds[s][j];
      float zf = z_lds[s][16 + j];
      float zc = z_lds[s][32 + j];
      float zo = z_lds[s][48 + j];
      float ig = fminf(fmaxf(0.2f * zi + 0.5f, 0.f), 1.f);
      float fg = fminf(fmaxf(0.2f * zf + 0.5f, 0.f), 1.f);
      float og = fminf(fmaxf(0.2f * zo + 0.5f, 0.f), 1.f);
      float chat = fg * c_st + ig * tanhf(zc);
      float hhat = og * tanhf(chat);
      float tt = t_0 + (float)(step + 1);
      float xx = tt - shift;
      float ph = (xx - period * floorf(xx / period)) / period;
      float kk = (ph <= 0.5f * ron) ? (2.f * ph / ron)
               : ((ph <= ron) ? (2.f - 2.f * ph / ron) : (ALPHA_ * ph));
      c_st = kk * chat + (1.f - kk) * c_st;
      h_st = kk * hhat + (1.f - kk) * h_st;
      // coherent (L2-bypass) h broadcast store
      unsigned hv = f2b(h_st);
      const unsigned short* hp = hbuf + nxt * (B_ * U_) + bb * U_ + uu;
      asm volatile("global_store_short %0, %1, off sc0 sc1"
                   :: "v"(hp), "v"(hv) : "memory");
      out[((long)bb * T_ + step) * U_ + uu] = h_st;  // cached, fire-and-forget
    }

    // ---- (5) split barrier: drain -> arrive -> overlap x prefetch -> wait ----
    if (step + 1 < T_) {
      asm volatile("s_waitcnt vmcnt(0)" ::: "memory");  // h stores at L3
      __syncthreads();                                   // all waves drained
      if (tid == 0) atomicAdd(mycnt, 1u);                // arrive (agent scope)
      stage_x(step + 1, xb ^ 1);                         // overlaps the wait
      if (tid == 0) {
        const unsigned tgt = (unsigned)(step + 1) * NSLICE;
        while (__hip_atomic_load(mycnt, __ATOMIC_RELAXED,
                                 __HIP_MEMORY_SCOPE_AGENT) < tgt)
          __builtin_amdgcn_s_sleep(1);
      }
      __syncthreads();
    }
  }
}

extern "C" void kernel_launch(void* const* d_in, const int* in_sizes, int n_in,
                              void* d_out, int out_size, void* d_ws,
                              size_t ws_size, hipStream_t stream) {
  const float* x    = (const float*)d_in[0];
  const float* h0   = (const float*)d_in[1];
  const float* c0   = (const float*)d_in[2];
  const float* t0   = (const float*)d_in[3];
  const float* kern = (const float*)d_in[4];
  const float* rker = (const float*)d_in[5];
  const float* bias = (const float*)d_in[6];
  const float* tg   = (const float*)d_in[7];
  float* out = (float*)d_out;

  char* ws = (char*)d_ws;
  unsigned short* wbf  = (unsigned short*)(ws + OFF_WBF);
  unsigned short* rbf  = (unsigned short*)(ws + OFF_RBF);
  unsigned short* hbuf = (unsigned short*)(ws + OFF_HBUF);
  unsigned* cnt        = (unsigned*)(ws + OFF_CNT);

  hipMemsetAsync(ws + OFF_CNT, 0, CNT_BYTES, stream);
  prep_kernel<<<1024, 256, 0, stream>>>(kern, rker, h0, wbf, rbf, hbuf);
  plstm_kernel<<<NWG, NTH, 0, stream>>>(x, h0, c0, t0, bias, tg, wbf, rbf,
                                        hbuf, cnt, out);
}